// Round 2
// baseline (241.952 us; speedup 1.0000x reference)
//
#include <hip/hip_runtime.h>
#include <math.h>

#define H 128
#define MROWS 64           // node rows per MLP block
#define XS 136             // padded row stride (ushorts) for bf16 LDS tiles
#define NB 8               // buckets per side (c and r)
#define NB2 64             // NB*NB
#define SB 256             // sort blocks (hist/scatter grid) — must match scan loop
#define ECH 256            // edge chunk per work-steal grab

typedef __attribute__((ext_vector_type(8))) short short8;
typedef __attribute__((ext_vector_type(4))) float floatx4;

__device__ __forceinline__ unsigned short f2bf(float f) {
    unsigned u = __float_as_uint(f);
    return (unsigned short)((u + 0x7FFFu + ((u >> 16) & 1u)) >> 16);  // RNE
}

__device__ __forceinline__ int bkt(int c, float s8) {
    int b = (int)((float)c * s8);          // s8 = NB/N; identical in hist+scatter
    return b > (NB - 1) ? (NB - 1) : b;
}

// ---------------------------------------------------------------------------
// Kernel 0: W1,W2 fp32 -> bf16 once.
// ---------------------------------------------------------------------------
__global__ void prep_weights(const float* __restrict__ W1,
                             const float* __restrict__ W2,
                             unsigned short* __restrict__ Wbf) {
    int i = blockIdx.x * 256 + threadIdx.x;       // 32768 total
    if (i < 16384)       Wbf[i] = f2bf(W1[i]);
    else if (i < 32768)  Wbf[i] = f2bf(W2[i - 16384]);
}

// ---------------------------------------------------------------------------
// Kernel 1: per-block histogram -> cnts[blk][64]. NO global atomics.
// ---------------------------------------------------------------------------
__global__ __launch_bounds__(256) void hist_k(const int* __restrict__ ei, int E,
                                              float s8, unsigned* __restrict__ cnts) {
    __shared__ unsigned h[NB2];
    if (threadIdx.x < NB2) h[threadIdx.x] = 0;
    __syncthreads();
    const int chunkE = (E + SB - 1) / SB;
    const int e0 = blockIdx.x * chunkE;
    const int e1 = min(e0 + chunkE, E);
    for (int e = e0 + (int)threadIdx.x; e < e1; e += 256) {
        int c = ei[e], r = ei[e + E];
        atomicAdd(&h[bkt(c, s8) * NB + bkt(r, s8)], 1u);
    }
    __syncthreads();
    if (threadIdx.x < NB2)
        cnts[blockIdx.x * NB2 + threadIdx.x] = h[threadIdx.x];
}

// ---------------------------------------------------------------------------
// Kernel 2 (1 wave): scan cnts -> per-(block,bucket) bases + bucket bounds.
// Also zeroes the edge work-steal cursors.
// ---------------------------------------------------------------------------
__global__ __launch_bounds__(64) void scan_k(const unsigned* __restrict__ cnts,
                                             unsigned* __restrict__ basetab,
                                             unsigned* __restrict__ bb64,
                                             unsigned* __restrict__ work) {
    const int b = threadIdx.x;                    // 0..63, bucket id
    unsigned tot = 0;
    #pragma unroll 4
    for (int blk = 0; blk < SB; ++blk) tot += cnts[blk * NB2 + b];
    // exclusive scan across the 64 lanes
    unsigned incl = tot;
    #pragma unroll
    for (int m = 1; m < 64; m <<= 1) {
        unsigned v = __shfl_up(incl, m);
        if (b >= m) incl += v;
    }
    const unsigned excl = incl - tot;
    bb64[b] = excl;
    if (b == 63) bb64[64] = incl;                 // == E
    unsigned run = excl;
    #pragma unroll 4
    for (int blk = 0; blk < SB; ++blk) {
        basetab[blk * NB2 + b] = run;
        run += cnts[blk * NB2 + b];
    }
    if (b < NB) work[b] = 0;
}

// ---------------------------------------------------------------------------
// Kernel 3: scatter via LDS cursors seeded from basetab. NO global atomics.
// ---------------------------------------------------------------------------
__global__ __launch_bounds__(256) void scatter_k(const int* __restrict__ ei, int E,
                                                 float s8,
                                                 const unsigned* __restrict__ basetab,
                                                 uint2* __restrict__ lst) {
    __shared__ unsigned cur[NB2];
    if (threadIdx.x < NB2)
        cur[threadIdx.x] = basetab[blockIdx.x * NB2 + threadIdx.x];
    __syncthreads();
    const int chunkE = (E + SB - 1) / SB;
    const int e0 = blockIdx.x * chunkE;
    const int e1 = min(e0 + chunkE, E);
    for (int e = e0 + (int)threadIdx.x; e < e1; e += 256) {
        int c = ei[e], r = ei[e + E];
        int b = bkt(c, s8) * NB + bkt(r, s8);
        unsigned pos = atomicAdd(&cur[b], 1u);    // LDS atomic only
        lst[pos] = make_uint2((unsigned)c | ((unsigned)r << 16), (unsigned)e);
    }
}

// ---------------------------------------------------------------------------
// Kernel 4: g = mlp(emb); register epilogue; qtab stored in the dot-invariant
// column permutation col' = l15*8 + nt (8 contiguous bytes per lane).
// ---------------------------------------------------------------------------
__global__ __launch_bounds__(256, 2) void mlp_mfma(
    const float* __restrict__ emb, const unsigned short* __restrict__ Wbf,
    const float* __restrict__ b1, const float* __restrict__ b2,
    signed char* __restrict__ qtab, float* __restrict__ scl, int N)
{
    __shared__ unsigned short Wl[H * XS];         // 34 KB, W1 then W2
    __shared__ unsigned short xs[MROWS * XS];     // 17 KB
    __shared__ unsigned short hs[MROWS * XS];     // 17 KB

    const int tid   = threadIdx.x;
    const int wave  = tid >> 6, lane = tid & 63;
    const int quad  = lane >> 4, l15 = lane & 15;
    const int node0 = blockIdx.x * MROWS;

    // ---- stage W1 (bf16, row-padded) ----
    {
        const float4* src = (const float4*)Wbf;
        #pragma unroll
        for (int i = 0; i < 8; ++i) {
            int cc = i * 256 + tid;
            int row = cc >> 4, c = cc & 15;
            *(float4*)(Wl + row * XS + c * 8) = src[cc];
        }
    }
    // ---- stage x rows (fp32 -> bf16) ----
    #pragma unroll
    for (int i = 0; i < 8; ++i) {
        int flat = i * 1024 + tid * 4;
        int rowl = flat >> 7, col = flat & 127;
        float4 v = make_float4(0.f, 0.f, 0.f, 0.f);
        if (node0 + rowl < N)
            v = *(const float4*)(emb + (size_t)(node0 + rowl) * H + col);
        ushort4 b;
        b.x = f2bf(v.x); b.y = f2bf(v.y); b.z = f2bf(v.z); b.w = f2bf(v.w);
        *(ushort4*)(xs + rowl * XS + col) = b;
    }
    __syncthreads();

    const int mrow = wave * 16 + l15;
    short8 afr[4];

    // ---- layer 1: hs = elu(x @ W1^T + b1) ----
    #pragma unroll
    for (int ks = 0; ks < 4; ++ks)
        afr[ks] = *(const short8*)(xs + mrow * XS + ks * 32 + quad * 8);
    #pragma unroll
    for (int nt = 0; nt < 8; ++nt) {
        floatx4 acc = {0.f, 0.f, 0.f, 0.f};
        #pragma unroll
        for (int ks = 0; ks < 4; ++ks) {
            short8 bfr = *(const short8*)(Wl + (nt * 16 + l15) * XS + ks * 32 + quad * 8);
            acc = __builtin_amdgcn_mfma_f32_16x16x32_bf16(afr[ks], bfr, acc, 0, 0, 0);
        }
        const int col = nt * 16 + l15;
        const float bb1 = b1[col];
        #pragma unroll
        for (int r = 0; r < 4; ++r) {
            float v = acc[r] + bb1;
            v = v > 0.f ? v : (__expf(v) - 1.f);  // ELU
            hs[(wave * 16 + quad * 4 + r) * XS + col] = f2bf(v);
        }
    }
    __syncthreads();                              // hs done; all W1 reads done

    // ---- A-frags for layer 2, then stage W2 over W1 ----
    #pragma unroll
    for (int ks = 0; ks < 4; ++ks)
        afr[ks] = *(const short8*)(hs + mrow * XS + ks * 32 + quad * 8);
    {
        const float4* src = (const float4*)(Wbf + 16384);
        #pragma unroll
        for (int i = 0; i < 8; ++i) {
            int cc = i * 256 + tid;
            int row = cc >> 4, c = cc & 15;
            *(float4*)(Wl + row * XS + c * 8) = src[cc];
        }
    }
    __syncthreads();

    // ---- layer 2 in registers: av[nt][r] = g, fused sum-sq and max-abs ----
    floatx4 av[8];
    float sq[4] = {0.f, 0.f, 0.f, 0.f};
    float am[4] = {0.f, 0.f, 0.f, 0.f};
    #pragma unroll
    for (int nt = 0; nt < 8; ++nt) {
        floatx4 acc = {0.f, 0.f, 0.f, 0.f};
        #pragma unroll
        for (int ks = 0; ks < 4; ++ks) {
            short8 bfr = *(const short8*)(Wl + (nt * 16 + l15) * XS + ks * 32 + quad * 8);
            acc = __builtin_amdgcn_mfma_f32_16x16x32_bf16(afr[ks], bfr, acc, 0, 0, 0);
        }
        const float bb2 = b2[nt * 16 + l15];
        #pragma unroll
        for (int r = 0; r < 4; ++r) {
            float v = acc[r] + bb2;
            av[nt][r] = v;
            sq[r] += v * v;
            am[r] = fmaxf(am[r], fabsf(v));
        }
    }
    // row reductions across the 16 l15 lanes (butterfly -> all lanes hold result)
    #pragma unroll
    for (int r = 0; r < 4; ++r) {
        float s = sq[r], a = am[r];
        #pragma unroll
        for (int m = 8; m; m >>= 1) {
            s += __shfl_xor(s, m);
            a = fmaxf(a, __shfl_xor(a, m));
        }
        sq[r] = s; am[r] = a;
    }
    // ---- quantize + store: lane owns 8 contiguous bytes at col' = l15*8+nt ----
    #pragma unroll
    for (int r = 0; r < 4; ++r) {
        const int row = wave * 16 + quad * 4 + r;
        const int G = node0 + row;
        if (G < N) {
            const float a = fmaxf(am[r], 1e-20f);
            if (l15 == 0) {
                float nn = sqrtf(sq[r]);
                if (nn < 1e-8f) nn = 1e-8f;
                scl[G] = a / (nn * 127.f);
            }
            const float qs = 127.f / a;
            unsigned pk0 = 0, pk1 = 0;
            #pragma unroll
            for (int nt = 0; nt < 4; ++nt) {
                int q = (int)rintf(av[nt][r] * qs);
                q = q > 127 ? 127 : (q < -127 ? -127 : q);
                pk0 |= ((unsigned)(q & 255)) << (8 * nt);
            }
            #pragma unroll
            for (int nt = 4; nt < 8; ++nt) {
                int q = (int)rintf(av[nt][r] * qs);
                q = q > 127 ? 127 : (q < -127 ? -127 : q);
                pk1 |= ((unsigned)(q & 255)) << (8 * (nt - 4));
            }
            *(uint2*)(qtab + (size_t)G * H + l15 * 8) = make_uint2(pk0, pk1);
        }
    }
}

// ---------------------------------------------------------------------------
// Kernel 5: edge cosine with HW-verified XCD affinity. Each block reads its
// actual XCD id (s_getreg HW_REG_XCC_ID) and serves c-bucket == XCD via a
// per-bucket work-steal cursor; after draining its own bucket it steals the
// others (correctness independent of block->XCD mapping).
// ---------------------------------------------------------------------------
__device__ __forceinline__ int dot4(unsigned a, unsigned b) {
    int s = 0;
    #pragma unroll
    for (int j = 0; j < 4; ++j)
        s += (int)((signed char)(a >> (8 * j))) * (int)((signed char)(b >> (8 * j)));
    return s;
}

__global__ __launch_bounds__(256) void edge_cos(
    const uint2* __restrict__ lst, const signed char* __restrict__ qtab,
    const float* __restrict__ scl, const unsigned* __restrict__ bb64,
    unsigned* __restrict__ work, float* __restrict__ out)
{
    __shared__ unsigned grab_s;
    const int tid  = threadIdx.x;
    const int sub  = tid & 7;
    const int slot = tid >> 3;                    // 32 edges per block-iter

    // HW_REG_XCC_ID: id=20, offset=0, size=32 -> imm = 20 | (31<<11) = 63508
    const unsigned myxcd = __builtin_amdgcn_s_getreg(63508) & (NB - 1);

    for (int k = 0; k < NB; ++k) {
        const int cb = (int)((myxcd + (unsigned)k) & (NB - 1));
        const unsigned s0 = bb64[cb * NB];
        const unsigned s1 = bb64[cb * NB + NB];
        while (true) {
            if (tid == 0) grab_s = atomicAdd(&work[cb], ECH);
            __syncthreads();
            const unsigned g = grab_s;
            __syncthreads();                      // grab_s reusable next round
            if (s0 + g >= s1) break;              // uniform exit
            #pragma unroll
            for (int it = 0; it < ECH / 32; ++it) {
                const unsigned idx = s0 + g + (unsigned)(it * 32 + slot);
                if (idx < s1) {
                    const uint2 pe = lst[idx];
                    const int c = (int)(pe.x & 0xFFFFu);
                    const int r = (int)(pe.x >> 16);
                    const uint4 ua = *(const uint4*)(qtab + (size_t)c * H + sub * 16);
                    const uint4 ub = *(const uint4*)(qtab + (size_t)r * H + sub * 16);
                    int s = dot4(ua.x, ub.x) + dot4(ua.y, ub.y)
                          + dot4(ua.z, ub.z) + dot4(ua.w, ub.w);
                    #pragma unroll
                    for (int m = 4; m; m >>= 1) s += __shfl_xor(s, m);
                    if (sub == 0) {
                        float vv = (float)s * scl[c] * scl[r];
                        __builtin_nontemporal_store(vv, out + pe.y);
                    }
                }
            }
        }
    }
}

// ---------------------------------------------------------------------------
extern "C" void kernel_launch(void* const* d_in, const int* in_sizes, int n_in,
                              void* d_out, int out_size, void* d_ws, size_t ws_size,
                              hipStream_t stream) {
    const float* emb = (const float*)d_in[0];
    const int*   ei  = (const int*)d_in[1];
    const float* W1  = (const float*)d_in[2];
    const float* b1  = (const float*)d_in[3];
    const float* W2  = (const float*)d_in[4];
    const float* b2  = (const float*)d_in[5];
    float*       out = (float*)d_out;

    const int N = in_sizes[0] / H;
    const int E = in_sizes[1] / 2;

    // workspace layout (N<65536 assumed for 16-bit index packing)
    unsigned short* Wbf     = (unsigned short*)d_ws;            // 64 KB
    signed char*    qtab    = (signed char*)(Wbf + 32768);      // N*H int8
    float*          sclp    = (float*)(qtab + (size_t)N * H);   // N fp32
    uint2*          lst     = (uint2*)(sclp + N);               // E * 8 B
    unsigned*       cnts    = (unsigned*)(lst + E);             // SB*64
    unsigned*       basetab = cnts + SB * NB2;                  // SB*64
    unsigned*       bb64    = basetab + SB * NB2;               // 65 (+pad)
    unsigned*       work    = bb64 + 72;                        // 8

    const float s8 = (float)NB / (float)N;

    prep_weights<<<128, 256, 0, stream>>>(W1, W2, Wbf);
    hist_k<<<SB, 256, 0, stream>>>(ei, E, s8, cnts);
    scan_k<<<1, 64, 0, stream>>>(cnts, basetab, bb64, work);
    scatter_k<<<SB, 256, 0, stream>>>(ei, E, s8, basetab, lst);
    mlp_mfma<<<(N + MROWS - 1) / MROWS, 256, 0, stream>>>(emb, Wbf, b1, b2, qtab, sclp, N);
    edge_cos<<<512, 256, 0, stream>>>(lst, qtab, sclp, bb64, work, out);
}

// Round 3
// 121.536 us; speedup vs baseline: 1.9908x; 1.9908x over previous
//
#include <hip/hip_runtime.h>
#include <math.h>

#define H 128
#define MROWS 64           // node rows per MLP block
#define XS 136             // padded row stride (ushorts) for bf16 LDS tiles

#if defined(__has_builtin)
# if __has_builtin(__builtin_amdgcn_sdot4)
#  define HAVE_SDOT4 1
# endif
#endif

typedef __attribute__((ext_vector_type(8))) short short8;
typedef __attribute__((ext_vector_type(4))) float floatx4;

__device__ __forceinline__ unsigned short f2bf(float f) {
    unsigned u = __float_as_uint(f);
    return (unsigned short)((u + 0x7FFFu + ((u >> 16) & 1u)) >> 16);  // RNE
}

// ---------------------------------------------------------------------------
// Kernel 0: W1,W2 fp32 -> bf16 once. Wbf[0..16383]=W1, [16384..]=W2
// ---------------------------------------------------------------------------
__global__ void prep_weights(const float* __restrict__ W1,
                             const float* __restrict__ W2,
                             unsigned short* __restrict__ Wbf) {
    int i = blockIdx.x * 256 + threadIdx.x;       // 32768 total
    if (i < 16384)       Wbf[i] = f2bf(W1[i]);
    else if (i < 32768)  Wbf[i] = f2bf(W2[i - 16384]);
}

// ---------------------------------------------------------------------------
// Kernel 1: g = mlp(emb); register epilogue; qtab stored in the dot-invariant
// column permutation col' = l15*8 + nt (8 contiguous bytes per lane).
// ---------------------------------------------------------------------------
__global__ __launch_bounds__(256, 2) void mlp_mfma(
    const float* __restrict__ emb, const unsigned short* __restrict__ Wbf,
    const float* __restrict__ b1, const float* __restrict__ b2,
    signed char* __restrict__ qtab, float* __restrict__ scl, int N)
{
    __shared__ unsigned short Wl[H * XS];         // 34 KB, W1 then W2
    __shared__ unsigned short xs[MROWS * XS];     // 17 KB
    __shared__ unsigned short hs[MROWS * XS];     // 17 KB

    const int tid   = threadIdx.x;
    const int wave  = tid >> 6, lane = tid & 63;
    const int quad  = lane >> 4, l15 = lane & 15;
    const int node0 = blockIdx.x * MROWS;

    // ---- stage W1 (bf16, row-padded) ----
    {
        const float4* src = (const float4*)Wbf;
        #pragma unroll
        for (int i = 0; i < 8; ++i) {
            int cc = i * 256 + tid;
            int row = cc >> 4, c = cc & 15;
            *(float4*)(Wl + row * XS + c * 8) = src[cc];
        }
    }
    // ---- stage x rows (fp32 -> bf16) ----
    #pragma unroll
    for (int i = 0; i < 8; ++i) {
        int flat = i * 1024 + tid * 4;
        int rowl = flat >> 7, col = flat & 127;
        float4 v = make_float4(0.f, 0.f, 0.f, 0.f);
        if (node0 + rowl < N)
            v = *(const float4*)(emb + (size_t)(node0 + rowl) * H + col);
        ushort4 b;
        b.x = f2bf(v.x); b.y = f2bf(v.y); b.z = f2bf(v.z); b.w = f2bf(v.w);
        *(ushort4*)(xs + rowl * XS + col) = b;
    }
    __syncthreads();

    const int mrow = wave * 16 + l15;
    short8 afr[4];

    // ---- layer 1: hs = elu(x @ W1^T + b1) ----
    #pragma unroll
    for (int ks = 0; ks < 4; ++ks)
        afr[ks] = *(const short8*)(xs + mrow * XS + ks * 32 + quad * 8);
    #pragma unroll
    for (int nt = 0; nt < 8; ++nt) {
        floatx4 acc = {0.f, 0.f, 0.f, 0.f};
        #pragma unroll
        for (int ks = 0; ks < 4; ++ks) {
            short8 bfr = *(const short8*)(Wl + (nt * 16 + l15) * XS + ks * 32 + quad * 8);
            acc = __builtin_amdgcn_mfma_f32_16x16x32_bf16(afr[ks], bfr, acc, 0, 0, 0);
        }
        const int col = nt * 16 + l15;
        const float bb1 = b1[col];
        #pragma unroll
        for (int r = 0; r < 4; ++r) {
            float v = acc[r] + bb1;
            v = v > 0.f ? v : (__expf(v) - 1.f);  // ELU
            hs[(wave * 16 + quad * 4 + r) * XS + col] = f2bf(v);
        }
    }
    __syncthreads();                              // hs done; all W1 reads done

    // ---- A-frags for layer 2, then stage W2 over W1 ----
    #pragma unroll
    for (int ks = 0; ks < 4; ++ks)
        afr[ks] = *(const short8*)(hs + mrow * XS + ks * 32 + quad * 8);
    {
        const float4* src = (const float4*)(Wbf + 16384);
        #pragma unroll
        for (int i = 0; i < 8; ++i) {
            int cc = i * 256 + tid;
            int row = cc >> 4, c = cc & 15;
            *(float4*)(Wl + row * XS + c * 8) = src[cc];
        }
    }
    __syncthreads();

    // ---- layer 2 in registers: av[nt][r] = g, fused sum-sq and max-abs ----
    floatx4 av[8];
    float sq[4] = {0.f, 0.f, 0.f, 0.f};
    float am[4] = {0.f, 0.f, 0.f, 0.f};
    #pragma unroll
    for (int nt = 0; nt < 8; ++nt) {
        floatx4 acc = {0.f, 0.f, 0.f, 0.f};
        #pragma unroll
        for (int ks = 0; ks < 4; ++ks) {
            short8 bfr = *(const short8*)(Wl + (nt * 16 + l15) * XS + ks * 32 + quad * 8);
            acc = __builtin_amdgcn_mfma_f32_16x16x32_bf16(afr[ks], bfr, acc, 0, 0, 0);
        }
        const float bb2 = b2[nt * 16 + l15];
        #pragma unroll
        for (int r = 0; r < 4; ++r) {
            float v = acc[r] + bb2;
            av[nt][r] = v;
            sq[r] += v * v;
            am[r] = fmaxf(am[r], fabsf(v));
        }
    }
    // row reductions across the 16 l15 lanes (butterfly -> all lanes hold result)
    #pragma unroll
    for (int r = 0; r < 4; ++r) {
        float s = sq[r], a = am[r];
        #pragma unroll
        for (int m = 8; m; m >>= 1) {
            s += __shfl_xor(s, m);
            a = fmaxf(a, __shfl_xor(a, m));
        }
        sq[r] = s; am[r] = a;
    }
    // ---- quantize + store: lane owns 8 contiguous bytes at col' = l15*8+nt ----
    #pragma unroll
    for (int r = 0; r < 4; ++r) {
        const int row = wave * 16 + quad * 4 + r;
        const int G = node0 + row;
        if (G < N) {
            const float a = fmaxf(am[r], 1e-20f);
            if (l15 == 0) {
                float nn = sqrtf(sq[r]);
                if (nn < 1e-8f) nn = 1e-8f;
                scl[G] = a / (nn * 127.f);
            }
            const float qs = 127.f / a;
            unsigned pk0 = 0, pk1 = 0;
            #pragma unroll
            for (int nt = 0; nt < 4; ++nt) {
                int q = (int)rintf(av[nt][r] * qs);
                q = q > 127 ? 127 : (q < -127 ? -127 : q);
                pk0 |= ((unsigned)(q & 255)) << (8 * nt);
            }
            #pragma unroll
            for (int nt = 4; nt < 8; ++nt) {
                int q = (int)rintf(av[nt][r] * qs);
                q = q > 127 ? 127 : (q < -127 ? -127 : q);
                pk1 |= ((unsigned)(q & 255)) << (8 * (nt - 4));
            }
            *(uint2*)(qtab + (size_t)G * H + l15 * 8) = make_uint2(pk0, pk1);
        }
    }
}

// ---------------------------------------------------------------------------
// Kernel 2: direct edge cosine, 8 lanes/edge, 4 edges per lane-group (ILP x4).
// NT index loads keep the ei stream from evicting qtab in L2.
// ---------------------------------------------------------------------------
__device__ __forceinline__ int dot4s(unsigned a, unsigned b) {
    int s = 0;
    #pragma unroll
    for (int j = 0; j < 4; ++j)
        s += (int)((signed char)(a >> (8 * j))) * (int)((signed char)(b >> (8 * j)));
    return s;
}

__device__ __forceinline__ int dot16(uint4 a, uint4 b) {
#if defined(HAVE_SDOT4)
    int s = __builtin_amdgcn_sdot4((int)a.x, (int)b.x, 0, false);
    s = __builtin_amdgcn_sdot4((int)a.y, (int)b.y, s, false);
    s = __builtin_amdgcn_sdot4((int)a.z, (int)b.z, s, false);
    s = __builtin_amdgcn_sdot4((int)a.w, (int)b.w, s, false);
    return s;
#else
    return dot4s(a.x, b.x) + dot4s(a.y, b.y) + dot4s(a.z, b.z) + dot4s(a.w, b.w);
#endif
}

__global__ __launch_bounds__(256) void edge_cos(
    const int* __restrict__ ei, const signed char* __restrict__ qtab,
    const float* __restrict__ scl, float* __restrict__ out, int E)
{
    const int tid = threadIdx.x;
    const int sub = tid & 7;
    const int g   = (blockIdx.x * 256 + tid) >> 3;   // lane-group id
    const int e0  = g * 4;
    if (e0 >= E) return;

    // ---- indices for 4 edges (NT: don't pollute L2) ----
    int cc[4], rr[4];
    #pragma unroll
    for (int k = 0; k < 4; ++k) {
        int e = e0 + k;
        if (e >= E) e = E - 1;                       // clamp; store predicated later
        cc[k] = __builtin_nontemporal_load(ei + e);
        rr[k] = __builtin_nontemporal_load(ei + e + E);
    }
    // ---- 8 independent row gathers in flight ----
    uint4 ua[4], ub[4];
    #pragma unroll
    for (int k = 0; k < 4; ++k) {
        ua[k] = *(const uint4*)(qtab + (size_t)cc[k] * H + sub * 16);
        ub[k] = *(const uint4*)(qtab + (size_t)rr[k] * H + sub * 16);
    }
    // ---- scales (L2-resident 200 KB table), issued alongside gathers ----
    float sc[4];
    #pragma unroll
    for (int k = 0; k < 4; ++k) sc[k] = scl[cc[k]] * scl[rr[k]];

    // ---- dots + 8-lane reduce + store ----
    #pragma unroll
    for (int k = 0; k < 4; ++k) {
        int s = dot16(ua[k], ub[k]);
        s += __shfl_xor(s, 4);
        s += __shfl_xor(s, 2);
        s += __shfl_xor(s, 1);
        if (sub == 0 && e0 + k < E)
            __builtin_nontemporal_store((float)s * sc[k], out + e0 + k);
    }
}

// ---------------------------------------------------------------------------
extern "C" void kernel_launch(void* const* d_in, const int* in_sizes, int n_in,
                              void* d_out, int out_size, void* d_ws, size_t ws_size,
                              hipStream_t stream) {
    const float* emb = (const float*)d_in[0];
    const int*   ei  = (const int*)d_in[1];
    const float* W1  = (const float*)d_in[2];
    const float* b1  = (const float*)d_in[3];
    const float* W2  = (const float*)d_in[4];
    const float* b2  = (const float*)d_in[5];
    float*       out = (float*)d_out;

    const int N = in_sizes[0] / H;
    const int E = in_sizes[1] / 2;

    unsigned short* Wbf  = (unsigned short*)d_ws;           // 32768 bf16 = 64 KB
    signed char*    qtab = (signed char*)(Wbf + 32768);     // N*H int8
    float*          sclp = (float*)(qtab + (size_t)N * H);  // N fp32

    prep_weights<<<128, 256, 0, stream>>>(W1, W2, Wbf);
    mlp_mfma<<<(N + MROWS - 1) / MROWS, 256, 0, stream>>>(emb, Wbf, b1, b2, qtab, sclp, N);
    edge_cos<<<(E + 127) / 128, 256, 0, stream>>>(ei, qtab, sclp, out, E);
}

// Round 4
// 119.838 us; speedup vs baseline: 2.0190x; 1.0142x over previous
//
#include <hip/hip_runtime.h>
#include <math.h>

#define H 128
#define MROWS 64           // node rows per MLP block
#define XS 136             // padded row stride (ushorts) for bf16 LDS tiles

#if defined(__has_builtin)
# if __has_builtin(__builtin_amdgcn_sdot4)
#  define HAVE_SDOT4 1
# endif
#endif

typedef __attribute__((ext_vector_type(8))) short short8;
typedef __attribute__((ext_vector_type(4))) float floatx4;

__device__ __forceinline__ unsigned short f2bf(float f) {
    unsigned u = __float_as_uint(f);
    return (unsigned short)((u + 0x7FFFu + ((u >> 16) & 1u)) >> 16);  // RNE
}

// ---------------------------------------------------------------------------
// Kernel 1: g = mlp(emb). W1/W2 staged from fp32 globals with inline cvt
// (bit-identical to the old prep_weights path). Layer-1 A-frags loaded
// directly from emb into registers (no xs tile). LDS = 51 KB -> 3 blocks/CU.
// qtab stored in the dot-invariant column permutation col' = l15*8 + nt.
// ---------------------------------------------------------------------------
__global__ __launch_bounds__(256, 3) void mlp_mfma(
    const float* __restrict__ emb, const float* __restrict__ W1,
    const float* __restrict__ W2, const float* __restrict__ b1,
    const float* __restrict__ b2,
    signed char* __restrict__ qtab, float* __restrict__ scl, int N)
{
    __shared__ unsigned short Wl[H * XS];         // 34 KB, W1 then W2
    __shared__ unsigned short hs[MROWS * XS];     // 17 KB

    const int tid   = threadIdx.x;
    const int wave  = tid >> 6, lane = tid & 63;
    const int quad  = lane >> 4, l15 = lane & 15;
    const int node0 = blockIdx.x * MROWS;

    const int  mrow = wave * 16 + l15;
    const int  grow = node0 + mrow;
    const bool rv   = grow < N;

    // ---- stage W1 (fp32 global -> bf16 LDS, row-padded) ----
    #pragma unroll
    for (int i = 0; i < 16; ++i) {
        int f = i * 1024 + tid * 4;               // 4096 float4 chunks
        int row = f >> 7, c = f & 127;
        float4 v = *(const float4*)(W1 + f);
        ushort4 b;
        b.x = f2bf(v.x); b.y = f2bf(v.y); b.z = f2bf(v.z); b.w = f2bf(v.w);
        *(ushort4*)(Wl + row * XS + c) = b;
    }

    // ---- layer-1 A-frags: direct from emb (global), cvt in registers ----
    short8 afr[4];
    #pragma unroll
    for (int ks = 0; ks < 4; ++ks) {
        float4 u0 = make_float4(0.f, 0.f, 0.f, 0.f);
        float4 u1 = make_float4(0.f, 0.f, 0.f, 0.f);
        if (rv) {
            const float* p = emb + (size_t)grow * H + ks * 32 + quad * 8;
            u0 = *(const float4*)p;
            u1 = *(const float4*)(p + 4);
        }
        short8 a;
        a[0] = (short)f2bf(u0.x); a[1] = (short)f2bf(u0.y);
        a[2] = (short)f2bf(u0.z); a[3] = (short)f2bf(u0.w);
        a[4] = (short)f2bf(u1.x); a[5] = (short)f2bf(u1.y);
        a[6] = (short)f2bf(u1.z); a[7] = (short)f2bf(u1.w);
        afr[ks] = a;
    }
    __syncthreads();                              // Wl(W1) ready

    // ---- layer 1: hs = elu(x @ W1^T + b1) ----
    #pragma unroll
    for (int nt = 0; nt < 8; ++nt) {
        floatx4 acc = {0.f, 0.f, 0.f, 0.f};
        #pragma unroll
        for (int ks = 0; ks < 4; ++ks) {
            short8 bfr = *(const short8*)(Wl + (nt * 16 + l15) * XS + ks * 32 + quad * 8);
            acc = __builtin_amdgcn_mfma_f32_16x16x32_bf16(afr[ks], bfr, acc, 0, 0, 0);
        }
        const int col = nt * 16 + l15;
        const float bb1 = b1[col];
        #pragma unroll
        for (int r = 0; r < 4; ++r) {
            float v = acc[r] + bb1;
            v = v > 0.f ? v : (__expf(v) - 1.f);  // ELU
            hs[(wave * 16 + quad * 4 + r) * XS + col] = f2bf(v);
        }
    }
    __syncthreads();                              // hs done; all W1 reads done

    // ---- A-frags for layer 2 (from hs), stage W2 over W1 concurrently ----
    #pragma unroll
    for (int ks = 0; ks < 4; ++ks)
        afr[ks] = *(const short8*)(hs + mrow * XS + ks * 32 + quad * 8);
    #pragma unroll
    for (int i = 0; i < 16; ++i) {
        int f = i * 1024 + tid * 4;
        int row = f >> 7, c = f & 127;
        float4 v = *(const float4*)(W2 + f);
        ushort4 b;
        b.x = f2bf(v.x); b.y = f2bf(v.y); b.z = f2bf(v.z); b.w = f2bf(v.w);
        *(ushort4*)(Wl + row * XS + c) = b;
    }
    __syncthreads();                              // Wl(W2) ready

    // ---- layer 2 in registers: av[nt][r] = g, fused sum-sq and max-abs ----
    floatx4 av[8];
    float sq[4] = {0.f, 0.f, 0.f, 0.f};
    float am[4] = {0.f, 0.f, 0.f, 0.f};
    #pragma unroll
    for (int nt = 0; nt < 8; ++nt) {
        floatx4 acc = {0.f, 0.f, 0.f, 0.f};
        #pragma unroll
        for (int ks = 0; ks < 4; ++ks) {
            short8 bfr = *(const short8*)(Wl + (nt * 16 + l15) * XS + ks * 32 + quad * 8);
            acc = __builtin_amdgcn_mfma_f32_16x16x32_bf16(afr[ks], bfr, acc, 0, 0, 0);
        }
        const float bb2 = b2[nt * 16 + l15];
        #pragma unroll
        for (int r = 0; r < 4; ++r) {
            float v = acc[r] + bb2;
            av[nt][r] = v;
            sq[r] += v * v;
            am[r] = fmaxf(am[r], fabsf(v));
        }
    }
    // row reductions across the 16 l15 lanes (butterfly -> all lanes hold result)
    #pragma unroll
    for (int r = 0; r < 4; ++r) {
        float s = sq[r], a = am[r];
        #pragma unroll
        for (int m = 8; m; m >>= 1) {
            s += __shfl_xor(s, m);
            a = fmaxf(a, __shfl_xor(a, m));
        }
        sq[r] = s; am[r] = a;
    }
    // ---- quantize + store: lane owns 8 contiguous bytes at col' = l15*8+nt ----
    #pragma unroll
    for (int r = 0; r < 4; ++r) {
        const int row = wave * 16 + quad * 4 + r;
        const int G = node0 + row;
        if (G < N) {
            const float a = fmaxf(am[r], 1e-20f);
            if (l15 == 0) {
                float nn = sqrtf(sq[r]);
                if (nn < 1e-8f) nn = 1e-8f;
                scl[G] = a / (nn * 127.f);
            }
            const float qs = 127.f / a;
            unsigned pk0 = 0, pk1 = 0;
            #pragma unroll
            for (int nt = 0; nt < 4; ++nt) {
                int q = (int)rintf(av[nt][r] * qs);
                q = q > 127 ? 127 : (q < -127 ? -127 : q);
                pk0 |= ((unsigned)(q & 255)) << (8 * nt);
            }
            #pragma unroll
            for (int nt = 4; nt < 8; ++nt) {
                int q = (int)rintf(av[nt][r] * qs);
                q = q > 127 ? 127 : (q < -127 ? -127 : q);
                pk1 |= ((unsigned)(q & 255)) << (8 * (nt - 4));
            }
            *(uint2*)(qtab + (size_t)G * H + l15 * 8) = make_uint2(pk0, pk1);
        }
    }
}

// ---------------------------------------------------------------------------
// Kernel 2: direct edge cosine, 8 lanes/edge, 4 edges per lane-group (ILP x4).
// NT index loads keep the ei stream from evicting qtab in L2.
// ---------------------------------------------------------------------------
__device__ __forceinline__ int dot4s(unsigned a, unsigned b) {
    int s = 0;
    #pragma unroll
    for (int j = 0; j < 4; ++j)
        s += (int)((signed char)(a >> (8 * j))) * (int)((signed char)(b >> (8 * j)));
    return s;
}

__device__ __forceinline__ int dot16(uint4 a, uint4 b) {
#if defined(HAVE_SDOT4)
    int s = __builtin_amdgcn_sdot4((int)a.x, (int)b.x, 0, false);
    s = __builtin_amdgcn_sdot4((int)a.y, (int)b.y, s, false);
    s = __builtin_amdgcn_sdot4((int)a.z, (int)b.z, s, false);
    s = __builtin_amdgcn_sdot4((int)a.w, (int)b.w, s, false);
    return s;
#else
    return dot4s(a.x, b.x) + dot4s(a.y, b.y) + dot4s(a.z, b.z) + dot4s(a.w, b.w);
#endif
}

__global__ __launch_bounds__(256) void edge_cos(
    const int* __restrict__ ei, const signed char* __restrict__ qtab,
    const float* __restrict__ scl, float* __restrict__ out, int E)
{
    const int tid = threadIdx.x;
    const int sub = tid & 7;
    const int g   = (blockIdx.x * 256 + tid) >> 3;   // lane-group id
    const int e0  = g * 4;
    if (e0 >= E) return;

    // ---- indices for 4 edges (NT: don't pollute L2) ----
    int cc[4], rr[4];
    #pragma unroll
    for (int k = 0; k < 4; ++k) {
        int e = e0 + k;
        if (e >= E) e = E - 1;                       // clamp; store predicated later
        cc[k] = __builtin_nontemporal_load(ei + e);
        rr[k] = __builtin_nontemporal_load(ei + e + E);
    }
    // ---- 8 independent row gathers in flight ----
    uint4 ua[4], ub[4];
    #pragma unroll
    for (int k = 0; k < 4; ++k) {
        ua[k] = *(const uint4*)(qtab + (size_t)cc[k] * H + sub * 16);
        ub[k] = *(const uint4*)(qtab + (size_t)rr[k] * H + sub * 16);
    }
    // ---- scales (L2-resident 200 KB table), issued alongside gathers ----
    float sc[4];
    #pragma unroll
    for (int k = 0; k < 4; ++k) sc[k] = scl[cc[k]] * scl[rr[k]];

    // ---- dots + 8-lane reduce + store ----
    #pragma unroll
    for (int k = 0; k < 4; ++k) {
        int s = dot16(ua[k], ub[k]);
        s += __shfl_xor(s, 4);
        s += __shfl_xor(s, 2);
        s += __shfl_xor(s, 1);
        if (sub == 0 && e0 + k < E)
            __builtin_nontemporal_store((float)s * sc[k], out + e0 + k);
    }
}

// ---------------------------------------------------------------------------
extern "C" void kernel_launch(void* const* d_in, const int* in_sizes, int n_in,
                              void* d_out, int out_size, void* d_ws, size_t ws_size,
                              hipStream_t stream) {
    const float* emb = (const float*)d_in[0];
    const int*   ei  = (const int*)d_in[1];
    const float* W1  = (const float*)d_in[2];
    const float* b1  = (const float*)d_in[3];
    const float* W2  = (const float*)d_in[4];
    const float* b2  = (const float*)d_in[5];
    float*       out = (float*)d_out;

    const int N = in_sizes[0] / H;
    const int E = in_sizes[1] / 2;

    signed char* qtab = (signed char*)d_ws;                 // N*H int8
    float*       sclp = (float*)(qtab + (size_t)N * H);     // N fp32

    mlp_mfma<<<(N + MROWS - 1) / MROWS, 256, 0, stream>>>(emb, W1, W2, b1, b2,
                                                          qtab, sclp, N);
    edge_cos<<<(E + 127) / 128, 256, 0, stream>>>(ei, qtab, sclp, out, E);
}